// Round 11
// baseline (304.648 us; speedup 1.0000x reference)
//
#include <hip/hip_runtime.h>
#include <hip/hip_bf16.h>
#include <stdint.h>

typedef unsigned int u32;
typedef unsigned char u8;
typedef unsigned long long u64;
typedef __attribute__((ext_vector_type(8))) int i32x8;
typedef __attribute__((ext_vector_type(4))) int i32x4;
typedef __attribute__((ext_vector_type(4))) float f32x4;

#define NROWS 8192    // 16*512
#define NCODES 4096
#define DIM 4096
#define BK 128
#define KSTEPS (DIM / BK)   // 32
#define BM 256
#define BN 256

// ---------------- workspace layout (bytes) ----------------
#define OFF_A      0UL
#define OFF_B      33554432UL
#define OFF_NORMS  50331648UL
#define OFF_RN     50348032UL
#define OFF_AMIN   50380800UL
#define OFF_COUNTS 50446336UL

__device__ __forceinline__ void stage16(const void* g, void* l) {
  __builtin_amdgcn_global_load_lds(
      (const __attribute__((address_space(1))) u32*)g,
      (__attribute__((address_space(3))) u32*)l, 16, 0, 0);
}

// float -> OCP e4m3fn, RNE, saturate to 448. Data is finite (no NaN path).
__device__ __forceinline__ u32 f2fp8(float f) {
  u32 u = __float_as_uint(f);
  u32 sign = (u >> 24) & 0x80u;
  u32 mag = u & 0x7FFFFFFFu;
  if (mag > 0x43E00000u) mag = 0x43E00000u;          // sat to 448
  u32 b;
  if (mag < 0x3C800000u) {                            // < 2^-6 : subnormal
    b = (u32)__float2int_rn(__uint_as_float(mag) * 512.0f);
  } else {
    u32 m = mag + 0x7FFFFu + ((mag >> 20) & 1u);      // RNE at 20-bit boundary
    u32 e = (m >> 23) - 127u;
    b = (((e + 7u) << 3) | ((m >> 20) & 7u)) & 0x7Fu;
  }
  return sign | b;
}

__device__ __forceinline__ u32 pack4(float4 v) {
  return f2fp8(v.x) | (f2fp8(v.y) << 8) | (f2fp8(v.z) << 16) | (f2fp8(v.w) << 24);
}

__device__ __forceinline__ float waveRed(float s) {
#pragma unroll
  for (int off = 32; off > 0; off >>= 1) s += __shfl_down(s, off);
  return s;
}

__device__ __forceinline__ i32x8 comb(i32x4 lo, i32x4 hi) {
  i32x8 r;
  r[0] = lo[0]; r[1] = lo[1]; r[2] = lo[2]; r[3] = lo[3];
  r[4] = hi[0]; r[5] = hi[1]; r[6] = hi[2]; r[7] = hi[3];
  return r;
}

// ---------------- inputs: fp32 -> fp8 + ||x||^2 per row (+ amin init) -------
__global__ void k_cvtA(const float4* __restrict__ in, u32* __restrict__ outA,
                       float* __restrict__ rn, u64* __restrict__ amin) {
  int r = blockIdx.x;
  if (threadIdx.x == 64) amin[r] = ~0ULL;   // fold k_init: one launch fewer
  const float4* src = in + (size_t)r * (DIM / 4);
  u32* dst = outA + (size_t)r * (DIM / 4);
  float s = 0.0f;
#pragma unroll
  for (int q = 0; q < 4; ++q) {
    int j = q * 256 + threadIdx.x;
    float4 v = src[j];
    s += v.x * v.x + v.y * v.y + v.z * v.z + v.w * v.w;
    dst[j] = pack4(v);
  }
  s = waveRed(s);
  __shared__ float red[4];
  int wid = threadIdx.x >> 6, lane = threadIdx.x & 63;
  if (lane == 0) red[wid] = s;
  __syncthreads();
  if (threadIdx.x == 0) rn[r] = red[0] + red[1] + red[2] + red[3];
}

// ---------------- codebook: fp32 -> fp8*4096 + ||e||^2 (+ counts init) ------
__global__ void k_cvtB(const float* __restrict__ cb, u32* __restrict__ Bb,
                       float* __restrict__ norms, u32* __restrict__ counts) {
  int row = blockIdx.x;
  if (threadIdx.x == 64) counts[row] = 0u;
  const float4* src = (const float4*)(cb + (size_t)row * DIM);
  u32* dst = Bb + (size_t)row * (DIM / 4);
  float s = 0.0f;
#pragma unroll
  for (int q = 0; q < 4; ++q) {
    int j = q * 256 + threadIdx.x;
    float4 v = src[j];
    s += v.x * v.x + v.y * v.y + v.z * v.z + v.w * v.w;
    float4 sv;
    sv.x = v.x * 4096.0f; sv.y = v.y * 4096.0f;
    sv.z = v.z * 4096.0f; sv.w = v.w * 4096.0f;
    dst[j] = pack4(sv);
  }
  s = waveRed(s);
  __shared__ float red[4];
  int wid = threadIdx.x >> 6, lane = threadIdx.x & 63;
  if (lane == 0) red[wid] = s;
  __syncthreads();
  if (threadIdx.x == 0) norms[row] = red[0] + red[1] + red[2] + red[3];
}

// ---------------- MX-fp8 GEMM (x . e^T) + per-row argmin ----------------
// 256x256 tile, BK=128 fp8, 8 waves (2 M x 4 N), wave tile 128x64,
// 16x16x128 f8f6f4 MFMA, unit scales. Chunk swizzle (pre-swizzled global
// source, linear LDS dest, swizzled reads).
// 8-PHASE (m201-style): per K-tile, 4 phases of {ds_read 2 A-frags (+4
// B-frags + full next-tile stage in phase 0); s_barrier; lgkmcnt(0)+
// sched_barrier; setprio(1); 8 MFMA; setprio(0); s_barrier}, then
// vmcnt(0)+barrier at tile end (prefetch issued 4 phases earlier ->
// drain is free). ds_reads of phase p+1 overlap the matrix-pipe drain
// of phase p's MFMAs -- the overlap the 2-phase schedule cannot express
// (guide m196/m198: +28-41%; T5 setprio only pays in this structure).
// All buffer indices are macro literals (R6-R9 spill lesson).
__launch_bounds__(512, 1)
__global__ void k_gemm_argmin(const u8* __restrict__ A,
                              const u8* __restrict__ B,
                              const float* __restrict__ norms,
                              u64* __restrict__ amin) {
  __shared__ u8 As[2][BM * BK];   // 2 x 32 KiB
  __shared__ u8 Bs[2][BN * BK];   // 2 x 32 KiB

  const int bm = blockIdx.x;
  const int bn = blockIdx.y;

  const int tid = threadIdx.x;
  const int w = tid >> 6;
  const int lane = tid & 63;
  const int wr = w >> 2, wc = w & 3;   // 2 x 4 wave grid
  const int g = lane >> 4, c = lane & 15;

  const size_t rowA0 = (size_t)bm * BM;
  const size_t rowB0 = (size_t)bn * BN;

  // stage-side swizzle: thread fills LDS chunk (tid&7) of row j*64+(tid>>3);
  // fetches global chunk (tid&7) ^ (row&7); row&7 == (tid>>3)&7 for all j.
  const int colb = (((tid & 7) ^ ((tid >> 3) & 7)) << 4);
  const int srow = tid >> 3;
  const u8* gA = A + rowA0 * DIM + colb;
  const u8* gB = B + rowB0 * DIM + colb;

  // read-side swizzle: fragment row&7 == c&7; halves at colo and colo^16.
  const int colo = (((2 * g) ^ (c & 7)) << 4);

  f32x4 acc[8][4] = {};

#define RDB(arr, row) comb(*(const i32x4*)&arr[(row)*BK + colo],          \
                           *(const i32x4*)&arr[(row)*BK + (colo ^ 16)])

#define STAGE(buf, kt_)                                                   \
  {                                                                       \
    _Pragma("unroll") for (int j = 0; j < 4; ++j) {                       \
      int o = j * 8192 + tid * 16;                                        \
      int row = j * 64 + srow;                                            \
      stage16(gA + (size_t)row * DIM + (size_t)(kt_)*BK,                  \
              (char*)As[buf] + o);                                        \
      stage16(gB + (size_t)row * DIM + (size_t)(kt_)*BK,                  \
              (char*)Bs[buf] + o);                                        \
    }                                                                     \
  }

#define MF(a, b_, cc) __builtin_amdgcn_mfma_scale_f32_16x16x128_f8f6f4(   \
    a, b_, cc, 0, 0, 0, 0x7F7F7F7F, 0, 0x7F7F7F7F)

#define PHTAIL(m0, m1)                                                    \
    __builtin_amdgcn_s_barrier();                                         \
    asm volatile("s_waitcnt lgkmcnt(0)" ::: "memory");                    \
    __builtin_amdgcn_sched_barrier(0);                                    \
    __builtin_amdgcn_s_setprio(1);                                        \
    acc[m0][0] = MF(a0, bv0, acc[m0][0]);                                 \
    acc[m0][1] = MF(a0, bv1, acc[m0][1]);                                 \
    acc[m0][2] = MF(a0, bv2, acc[m0][2]);                                 \
    acc[m0][3] = MF(a0, bv3, acc[m0][3]);                                 \
    acc[m1][0] = MF(a1, bv0, acc[m1][0]);                                 \
    acc[m1][1] = MF(a1, bv1, acc[m1][1]);                                 \
    acc[m1][2] = MF(a1, bv2, acc[m1][2]);                                 \
    acc[m1][3] = MF(a1, bv3, acc[m1][3]);                                 \
    __builtin_amdgcn_s_setprio(0);                                        \
    __builtin_amdgcn_s_barrier();

// One K-tile from buffer `b` (literal 0/1); optionally stage tile kt_
// into buffer b^1 during phase 0.
#define TILE(b, stg, kt_)                                                 \
  {                                                                       \
    i32x8 bv0, bv1, bv2, bv3, a0, a1;                                     \
    bv0 = RDB(Bs[b], wc * 64 + 0 + c);                                    \
    bv1 = RDB(Bs[b], wc * 64 + 16 + c);                                   \
    bv2 = RDB(Bs[b], wc * 64 + 32 + c);                                   \
    bv3 = RDB(Bs[b], wc * 64 + 48 + c);                                   \
    a0 = RDB(As[b], wr * 128 + 0 + c);                                    \
    a1 = RDB(As[b], wr * 128 + 16 + c);                                   \
    if (stg) STAGE(b ^ 1, kt_);                                           \
    PHTAIL(0, 1)                                                          \
    a0 = RDB(As[b], wr * 128 + 32 + c);                                   \
    a1 = RDB(As[b], wr * 128 + 48 + c);                                   \
    PHTAIL(2, 3)                                                          \
    a0 = RDB(As[b], wr * 128 + 64 + c);                                   \
    a1 = RDB(As[b], wr * 128 + 80 + c);                                   \
    PHTAIL(4, 5)                                                          \
    a0 = RDB(As[b], wr * 128 + 96 + c);                                   \
    a1 = RDB(As[b], wr * 128 + 112 + c);                                  \
    PHTAIL(6, 7)                                                          \
  }

#define VM0BAR()                                                          \
  asm volatile("s_waitcnt vmcnt(0)" ::: "memory");                        \
  __builtin_amdgcn_s_barrier();                                           \
  __builtin_amdgcn_sched_barrier(0);

  // ---- prologue: stage tile 0 into buffer 0 ----
  STAGE(0, 0);
  VM0BAR();

#pragma unroll 1
  for (int kt2 = 0; kt2 < 15; ++kt2) {
    TILE(0, 1, 2 * kt2 + 1);   // compute tile 2k from buf0, stage 2k+1
    VM0BAR();                  // buf1 landed (issued 4 phases ago: free)
    TILE(1, 1, 2 * kt2 + 2);   // compute tile 2k+1 from buf1, stage 2k+2
    VM0BAR();                  // buf0 landed
  }
  TILE(0, 1, 31);              // tile 30, stage 31
  VM0BAR();
  TILE(1, 0, 0);               // tile 31, no stage

#undef RDB
#undef STAGE
#undef MF
#undef PHTAIL
#undef TILE
#undef VM0BAR

  // epilogue: d = ||e||^2 - (2/4096)*acc ; argmin over this block's 256 cols
  const int rowBase = bm * BM + wr * 128;
  const int colBase = bn * BN + wc * 64;
  float nr[4];
#pragma unroll
  for (int n = 0; n < 4; ++n) nr[n] = norms[colBase + n * 16 + c];

#pragma unroll
  for (int m = 0; m < 8; ++m) {
#pragma unroll
    for (int j = 0; j < 4; ++j) {
      u64 key = ~0ULL;
#pragma unroll
      for (int n = 0; n < 4; ++n) {
        float d = nr[n] - acc[m][n][j] * 4.8828125e-4f;   // 2/4096
        u32 u = __float_as_uint(d);
        u = (u & 0x80000000u) ? ~u : (u | 0x80000000u);
        u64 k2 = ((u64)u << 32) | (u32)(colBase + n * 16 + c);
        if (k2 < key) key = k2;
      }
#pragma unroll
      for (int off = 1; off < 16; off <<= 1) {
        u64 o = __shfl_xor(key, off);
        if (o < key) key = o;
      }
      if (c == 0) atomicMin(&amin[rowBase + m * 16 + g * 4 + j], key);
    }
  }
}

// ---------------- gather -> output + counts ----------------
__global__ void k_out(const float4* __restrict__ cb, const u64* __restrict__ amin,
                      float4* __restrict__ out, u32* __restrict__ counts) {
  int r = blockIdx.x;
  u32 idx = (u32)(amin[r] & 0xFFFFFFFFu);
  if (threadIdx.x == 0) atomicAdd(&counts[idx], 1u);
  const float4* crow = cb + (size_t)idx * (DIM / 4);
  float4* orow = out + (size_t)r * (DIM / 4);
#pragma unroll
  for (int q = 0; q < 4; ++q) {
    int j = q * 256 + threadIdx.x;
    orow[j] = crow[j];
  }
}

// ---------------- finalize: loss (from distances) + perplexity ----------------
__global__ void k_final(const u32* __restrict__ counts, const u64* __restrict__ amin,
                        const float* __restrict__ rn, float* __restrict__ out) {
  float acc = 0.0f;
  for (int r = threadIdx.x; r < NROWS; r += 256) {
    u32 u = (u32)(amin[r] >> 32);
    u32 b = (u & 0x80000000u) ? (u & 0x7FFFFFFFu) : ~u;  // undo sortable map
    acc += __uint_as_float(b) + rn[r];   // d_min + ||x||^2 = ||x - e||^2
  }
  float ent = 0.0f;
  for (int i = threadIdx.x; i < NCODES; i += 256) {
    float p = (float)counts[i] * (1.0f / (float)NROWS);
    ent -= p * logf(p + 1e-10f);
  }
  acc = waveRed(acc);
  ent = waveRed(ent);
  __shared__ float ra[4], re[4];
  int wid = threadIdx.x >> 6, lane = threadIdx.x & 63;
  if (lane == 0) { ra[wid] = acc; re[wid] = ent; }
  __syncthreads();
  if (threadIdx.x == 0) {
    float sse = ra[0] + ra[1] + ra[2] + ra[3];
    float e = re[0] + re[1] + re[2] + re[3];
    out[(size_t)NROWS * DIM] = 1.25f * sse * (1.0f / (float)((size_t)NROWS * DIM));
    out[(size_t)NROWS * DIM + 1] = expf(e);
  }
}

extern "C" void kernel_launch(void* const* d_in, const int* in_sizes, int n_in,
                              void* d_out, int out_size, void* d_ws, size_t ws_size,
                              hipStream_t stream) {
  const float* d_inputs = (const float*)d_in[0];
  const float* d_cb = (const float*)d_in[1];
  float* out = (float*)d_out;
  char* ws = (char*)d_ws;

  u8* A = (u8*)(ws + OFF_A);
  u8* B = (u8*)(ws + OFF_B);
  float* norms = (float*)(ws + OFF_NORMS);
  float* rn = (float*)(ws + OFF_RN);
  u64* amin = (u64*)(ws + OFF_AMIN);
  u32* counts = (u32*)(ws + OFF_COUNTS);

  k_cvtA<<<NROWS, 256, 0, stream>>>((const float4*)d_inputs, (u32*)A, rn, amin);
  k_cvtB<<<NCODES, 256, 0, stream>>>(d_cb, (u32*)B, norms, counts);
  dim3 grid(NROWS / BM, NCODES / BN);
  k_gemm_argmin<<<grid, 512, 0, stream>>>(A, B, norms, amin);
  k_out<<<NROWS, 256, 0, stream>>>((const float4*)d_cb, amin, (float4*)out, counts);
  k_final<<<1, 256, 0, stream>>>(counts, amin, rn, out);
}

// Round 12
// 291.378 us; speedup vs baseline: 1.0455x; 1.0455x over previous
//
#include <hip/hip_runtime.h>
#include <hip/hip_bf16.h>
#include <stdint.h>

typedef unsigned int u32;
typedef unsigned char u8;
typedef unsigned long long u64;
typedef __attribute__((ext_vector_type(8))) int i32x8;
typedef __attribute__((ext_vector_type(4))) int i32x4;
typedef __attribute__((ext_vector_type(4))) float f32x4;

#define NROWS 8192    // 16*512
#define NCODES 4096
#define DIM 4096
#define BK 128
#define KSTEPS (DIM / BK)   // 32
#define BM 256
#define BN 256

// ---------------- workspace layout (bytes) ----------------
#define OFF_A      0UL
#define OFF_B      33554432UL
#define OFF_NORMS  50331648UL
#define OFF_RN     50348032UL
#define OFF_AMIN   50380800UL
#define OFF_COUNTS 50446336UL

__device__ __forceinline__ void stage16(const void* g, void* l) {
  __builtin_amdgcn_global_load_lds(
      (const __attribute__((address_space(1))) u32*)g,
      (__attribute__((address_space(3))) u32*)l, 16, 0, 0);
}

// float -> OCP e4m3fn, RNE, saturate to 448. Data is finite (no NaN path).
__device__ __forceinline__ u32 f2fp8(float f) {
  u32 u = __float_as_uint(f);
  u32 sign = (u >> 24) & 0x80u;
  u32 mag = u & 0x7FFFFFFFu;
  if (mag > 0x43E00000u) mag = 0x43E00000u;          // sat to 448
  u32 b;
  if (mag < 0x3C800000u) {                            // < 2^-6 : subnormal
    b = (u32)__float2int_rn(__uint_as_float(mag) * 512.0f);
  } else {
    u32 m = mag + 0x7FFFFu + ((mag >> 20) & 1u);      // RNE at 20-bit boundary
    u32 e = (m >> 23) - 127u;
    b = (((e + 7u) << 3) | ((m >> 20) & 7u)) & 0x7Fu;
  }
  return sign | b;
}

__device__ __forceinline__ u32 pack4(float4 v) {
  return f2fp8(v.x) | (f2fp8(v.y) << 8) | (f2fp8(v.z) << 16) | (f2fp8(v.w) << 24);
}

__device__ __forceinline__ float waveRed(float s) {
#pragma unroll
  for (int off = 32; off > 0; off >>= 1) s += __shfl_down(s, off);
  return s;
}

__device__ __forceinline__ i32x8 comb(i32x4 lo, i32x4 hi) {
  i32x8 r;
  r[0] = lo[0]; r[1] = lo[1]; r[2] = lo[2]; r[3] = lo[3];
  r[4] = hi[0]; r[5] = hi[1]; r[6] = hi[2]; r[7] = hi[3];
  return r;
}

// ---------------- inputs: fp32 -> fp8 + ||x||^2 per row (+ amin init) -------
__global__ void k_cvtA(const float4* __restrict__ in, u32* __restrict__ outA,
                       float* __restrict__ rn, u64* __restrict__ amin) {
  int r = blockIdx.x;
  if (threadIdx.x == 64) amin[r] = ~0ULL;   // fold k_init: one launch fewer
  const float4* src = in + (size_t)r * (DIM / 4);
  u32* dst = outA + (size_t)r * (DIM / 4);
  float s = 0.0f;
#pragma unroll
  for (int q = 0; q < 4; ++q) {
    int j = q * 256 + threadIdx.x;
    float4 v = src[j];
    s += v.x * v.x + v.y * v.y + v.z * v.z + v.w * v.w;
    dst[j] = pack4(v);
  }
  s = waveRed(s);
  __shared__ float red[4];
  int wid = threadIdx.x >> 6, lane = threadIdx.x & 63;
  if (lane == 0) red[wid] = s;
  __syncthreads();
  if (threadIdx.x == 0) rn[r] = red[0] + red[1] + red[2] + red[3];
}

// ---------------- codebook: fp32 -> fp8*4096 + ||e||^2 (+ counts init) ------
__global__ void k_cvtB(const float* __restrict__ cb, u32* __restrict__ Bb,
                       float* __restrict__ norms, u32* __restrict__ counts) {
  int row = blockIdx.x;
  if (threadIdx.x == 64) counts[row] = 0u;
  const float4* src = (const float4*)(cb + (size_t)row * DIM);
  u32* dst = Bb + (size_t)row * (DIM / 4);
  float s = 0.0f;
#pragma unroll
  for (int q = 0; q < 4; ++q) {
    int j = q * 256 + threadIdx.x;
    float4 v = src[j];
    s += v.x * v.x + v.y * v.y + v.z * v.z + v.w * v.w;
    float4 sv;
    sv.x = v.x * 4096.0f; sv.y = v.y * 4096.0f;
    sv.z = v.z * 4096.0f; sv.w = v.w * 4096.0f;
    dst[j] = pack4(sv);
  }
  s = waveRed(s);
  __shared__ float red[4];
  int wid = threadIdx.x >> 6, lane = threadIdx.x & 63;
  if (lane == 0) red[wid] = s;
  __syncthreads();
  if (threadIdx.x == 0) norms[row] = red[0] + red[1] + red[2] + red[3];
}

// ---------------- MX-fp8 GEMM (x . e^T) + per-row argmin ----------------
// 256x256 tile, BK=128 fp8, 8 waves (2 M x 4 N), wave tile 128x64,
// 16x16x128 f8f6f4 MFMA, unit scales. Chunk swizzle (pre-swizzled global
// source, linear LDS dest, swizzled reads). 8-phase m201-style schedule
// as R11, but with the ADDRESSING PUT ON A DIET so the arch-VGPR side
// fits in 128 (unified file: acc[8][4]=128 AGPR + 128 arch = 256/wave):
//  - 8 persistent global stage pointers, advanced += BK per stage (no
//    per-tile row*DIM+kt*BK recomputation)
//  - flattened LDS + 4 base pointers; every ds_read address is
//    base + compile-time literal (buf*32768 + frag*2048) -> folds into
//    ds_read_b128 offset:N (m203 pattern)
//  - buffer ids are macro literals everywhere (R6-R9 spill lesson)
// R11 spilled ~5 arch regs (137 MB scratch) purely from fat staging
// address code; schedule itself was never cleanly measured until now.
__launch_bounds__(512, 1)
__global__ void k_gemm_argmin(const u8* __restrict__ A,
                              const u8* __restrict__ B,
                              const float* __restrict__ norms,
                              u64* __restrict__ amin) {
  __shared__ u8 As[2 * BM * BK];   // 64 KiB (2 buffers x 32 KiB)
  __shared__ u8 Bs[2 * BN * BK];   // 64 KiB

  const int bm = blockIdx.x;
  const int bn = blockIdx.y;

  const int tid = threadIdx.x;
  const int w = tid >> 6;
  const int lane = tid & 63;
  const int wr = w >> 2, wc = w & 3;   // 2 x 4 wave grid
  const int g = lane >> 4, c = lane & 15;

  // stage-side swizzle: thread fills LDS chunk (tid&7) of row j*64+(tid>>3);
  // fetches global chunk (tid&7) ^ (row&7); row&7 == (tid>>3)&7 for all j.
  const int colb = (((tid & 7) ^ ((tid >> 3) & 7)) << 4);
  const int srow = tid >> 3;

  // persistent stage pointers (advance by BK per stage call)
  const u8* pgA0 = A + ((size_t)bm * BM + 0 * 64 + srow) * DIM + colb;
  const u8* pgA1 = A + ((size_t)bm * BM + 1 * 64 + srow) * DIM + colb;
  const u8* pgA2 = A + ((size_t)bm * BM + 2 * 64 + srow) * DIM + colb;
  const u8* pgA3 = A + ((size_t)bm * BM + 3 * 64 + srow) * DIM + colb;
  const u8* pgB0 = B + ((size_t)bn * BN + 0 * 64 + srow) * DIM + colb;
  const u8* pgB1 = B + ((size_t)bn * BN + 1 * 64 + srow) * DIM + colb;
  const u8* pgB2 = B + ((size_t)bn * BN + 2 * 64 + srow) * DIM + colb;
  const u8* pgB3 = B + ((size_t)bn * BN + 3 * 64 + srow) * DIM + colb;
  char* ldsA = (char*)As + tid * 16;
  char* ldsB = (char*)Bs + tid * 16;

  // read-side swizzle: fragment row&7 == c&7; halves at colo and colo^16.
  const int colo = (((2 * g) ^ (c & 7)) << 4);
  const u8* pA = &As[(wr * 128 + c) * BK + colo];
  const u8* pAx = &As[(wr * 128 + c) * BK + (colo ^ 16)];
  const u8* pB = &Bs[(wc * 64 + c) * BK + colo];
  const u8* pBx = &Bs[(wc * 64 + c) * BK + (colo ^ 16)];

  f32x4 acc[8][4] = {};

  // all offsets compile-time: buf*32768 + frag*2048
#define RD_A(b_, m_) comb(*(const i32x4*)(pA + ((b_)*32768 + (m_)*2048)),  \
                          *(const i32x4*)(pAx + ((b_)*32768 + (m_)*2048)))
#define RD_B(b_, n_) comb(*(const i32x4*)(pB + ((b_)*32768 + (n_)*2048)),  \
                          *(const i32x4*)(pBx + ((b_)*32768 + (n_)*2048)))

#define STAGE(buf)                                                        \
  {                                                                       \
    stage16(pgA0, ldsA + (buf)*32768 + 0 * 8192); pgA0 += BK;             \
    stage16(pgB0, ldsB + (buf)*32768 + 0 * 8192); pgB0 += BK;             \
    stage16(pgA1, ldsA + (buf)*32768 + 1 * 8192); pgA1 += BK;             \
    stage16(pgB1, ldsB + (buf)*32768 + 1 * 8192); pgB1 += BK;             \
    stage16(pgA2, ldsA + (buf)*32768 + 2 * 8192); pgA2 += BK;             \
    stage16(pgB2, ldsB + (buf)*32768 + 2 * 8192); pgB2 += BK;             \
    stage16(pgA3, ldsA + (buf)*32768 + 3 * 8192); pgA3 += BK;             \
    stage16(pgB3, ldsB + (buf)*32768 + 3 * 8192); pgB3 += BK;             \
  }

#define MF(a, b_, cc) __builtin_amdgcn_mfma_scale_f32_16x16x128_f8f6f4(   \
    a, b_, cc, 0, 0, 0, 0x7F7F7F7F, 0, 0x7F7F7F7F)

#define PHTAIL(m0, m1)                                                    \
    __builtin_amdgcn_s_barrier();                                         \
    asm volatile("s_waitcnt lgkmcnt(0)" ::: "memory");                    \
    __builtin_amdgcn_sched_barrier(0);                                    \
    __builtin_amdgcn_s_setprio(1);                                        \
    acc[m0][0] = MF(a0, bv0, acc[m0][0]);                                 \
    acc[m0][1] = MF(a0, bv1, acc[m0][1]);                                 \
    acc[m0][2] = MF(a0, bv2, acc[m0][2]);                                 \
    acc[m0][3] = MF(a0, bv3, acc[m0][3]);                                 \
    acc[m1][0] = MF(a1, bv0, acc[m1][0]);                                 \
    acc[m1][1] = MF(a1, bv1, acc[m1][1]);                                 \
    acc[m1][2] = MF(a1, bv2, acc[m1][2]);                                 \
    acc[m1][3] = MF(a1, bv3, acc[m1][3]);                                 \
    __builtin_amdgcn_s_setprio(0);                                        \
    __builtin_amdgcn_s_barrier();

// One K-tile from buffer b (literal 0/1); stg literal 0/1 controls
// whether the next tile is staged into buffer b^1 during phase 0.
#define TILE(b, stg)                                                      \
  {                                                                       \
    i32x8 bv0, bv1, bv2, bv3, a0, a1;                                     \
    bv0 = RD_B(b, 0);                                                     \
    bv1 = RD_B(b, 1);                                                     \
    bv2 = RD_B(b, 2);                                                     \
    bv3 = RD_B(b, 3);                                                     \
    a0 = RD_A(b, 0);                                                      \
    a1 = RD_A(b, 1);                                                      \
    if (stg) STAGE((b) ^ 1);                                              \
    PHTAIL(0, 1)                                                          \
    a0 = RD_A(b, 2);                                                      \
    a1 = RD_A(b, 3);                                                      \
    PHTAIL(2, 3)                                                          \
    a0 = RD_A(b, 4);                                                      \
    a1 = RD_A(b, 5);                                                      \
    PHTAIL(4, 5)                                                          \
    a0 = RD_A(b, 6);                                                      \
    a1 = RD_A(b, 7);                                                      \
    PHTAIL(6, 7)                                                          \
  }

#define VM0BAR()                                                          \
  asm volatile("s_waitcnt vmcnt(0)" ::: "memory");                        \
  __builtin_amdgcn_s_barrier();                                           \
  __builtin_amdgcn_sched_barrier(0);

  // ---- prologue: stage tile 0 into buffer 0 ----
  STAGE(0);
  VM0BAR();

#pragma unroll 1
  for (int kt2 = 0; kt2 < 15; ++kt2) {
    TILE(0, 1);   // compute tile 2k from buf0; stage 2k+1 -> buf1
    VM0BAR();     // buf1 landed (issued 4 phases ago: drain ~free)
    TILE(1, 1);   // compute tile 2k+1 from buf1; stage 2k+2 -> buf0
    VM0BAR();     // buf0 landed
  }
  TILE(0, 1);     // tile 30; stage 31 -> buf1
  VM0BAR();
  TILE(1, 0);     // tile 31, no stage

#undef RD_A
#undef RD_B
#undef STAGE
#undef MF
#undef PHTAIL
#undef TILE
#undef VM0BAR

  // epilogue: d = ||e||^2 - (2/4096)*acc ; argmin over this block's 256 cols
  const int rowBase = bm * BM + wr * 128;
  const int colBase = bn * BN + wc * 64;
  float nr[4];
#pragma unroll
  for (int n = 0; n < 4; ++n) nr[n] = norms[colBase + n * 16 + c];

#pragma unroll
  for (int m = 0; m < 8; ++m) {
#pragma unroll
    for (int j = 0; j < 4; ++j) {
      u64 key = ~0ULL;
#pragma unroll
      for (int n = 0; n < 4; ++n) {
        float d = nr[n] - acc[m][n][j] * 4.8828125e-4f;   // 2/4096
        u32 u = __float_as_uint(d);
        u = (u & 0x80000000u) ? ~u : (u | 0x80000000u);
        u64 k2 = ((u64)u << 32) | (u32)(colBase + n * 16 + c);
        if (k2 < key) key = k2;
      }
#pragma unroll
      for (int off = 1; off < 16; off <<= 1) {
        u64 o = __shfl_xor(key, off);
        if (o < key) key = o;
      }
      if (c == 0) atomicMin(&amin[rowBase + m * 16 + g * 4 + j], key);
    }
  }
}

// ---------------- gather -> output + counts ----------------
__global__ void k_out(const float4* __restrict__ cb, const u64* __restrict__ amin,
                      float4* __restrict__ out, u32* __restrict__ counts) {
  int r = blockIdx.x;
  u32 idx = (u32)(amin[r] & 0xFFFFFFFFu);
  if (threadIdx.x == 0) atomicAdd(&counts[idx], 1u);
  const float4* crow = cb + (size_t)idx * (DIM / 4);
  float4* orow = out + (size_t)r * (DIM / 4);
#pragma unroll
  for (int q = 0; q < 4; ++q) {
    int j = q * 256 + threadIdx.x;
    orow[j] = crow[j];
  }
}

// ---------------- finalize: loss (from distances) + perplexity ----------------
__global__ void k_final(const u32* __restrict__ counts, const u64* __restrict__ amin,
                        const float* __restrict__ rn, float* __restrict__ out) {
  float acc = 0.0f;
  for (int r = threadIdx.x; r < NROWS; r += 256) {
    u32 u = (u32)(amin[r] >> 32);
    u32 b = (u & 0x80000000u) ? (u & 0x7FFFFFFFu) : ~u;  // undo sortable map
    acc += __uint_as_float(b) + rn[r];   // d_min + ||x||^2 = ||x - e||^2
  }
  float ent = 0.0f;
  for (int i = threadIdx.x; i < NCODES; i += 256) {
    float p = (float)counts[i] * (1.0f / (float)NROWS);
    ent -= p * logf(p + 1e-10f);
  }
  acc = waveRed(acc);
  ent = waveRed(ent);
  __shared__ float ra[4], re[4];
  int wid = threadIdx.x >> 6, lane = threadIdx.x & 63;
  if (lane == 0) { ra[wid] = acc; re[wid] = ent; }
  __syncthreads();
  if (threadIdx.x == 0) {
    float sse = ra[0] + ra[1] + ra[2] + ra[3];
    float e = re[0] + re[1] + re[2] + re[3];
    out[(size_t)NROWS * DIM] = 1.25f * sse * (1.0f / (float)((size_t)NROWS * DIM));
    out[(size_t)NROWS * DIM + 1] = expf(e);
  }
}

extern "C" void kernel_launch(void* const* d_in, const int* in_sizes, int n_in,
                              void* d_out, int out_size, void* d_ws, size_t ws_size,
                              hipStream_t stream) {
  const float* d_inputs = (const float*)d_in[0];
  const float* d_cb = (const float*)d_in[1];
  float* out = (float*)d_out;
  char* ws = (char*)d_ws;

  u8* A = (u8*)(ws + OFF_A);
  u8* B = (u8*)(ws + OFF_B);
  float* norms = (float*)(ws + OFF_NORMS);
  float* rn = (float*)(ws + OFF_RN);
  u64* amin = (u64*)(ws + OFF_AMIN);
  u32* counts = (u32*)(ws + OFF_COUNTS);

  k_cvtA<<<NROWS, 256, 0, stream>>>((const float4*)d_inputs, (u32*)A, rn, amin);
  k_cvtB<<<NCODES, 256, 0, stream>>>(d_cb, (u32*)B, norms, counts);
  dim3 grid(NROWS / BM, NCODES / BN);
  k_gemm_argmin<<<grid, 512, 0, stream>>>(A, B, norms, amin);
  k_out<<<NROWS, 256, 0, stream>>>((const float4*)d_cb, amin, (float4*)out, counts);
  k_final<<<1, 256, 0, stream>>>(counts, amin, rn, out);
}

// Round 13
// 284.876 us; speedup vs baseline: 1.0694x; 1.0228x over previous
//
#include <hip/hip_runtime.h>
#include <hip/hip_bf16.h>
#include <stdint.h>

typedef unsigned int u32;
typedef unsigned char u8;
typedef unsigned long long u64;
typedef __attribute__((ext_vector_type(8))) int i32x8;
typedef __attribute__((ext_vector_type(4))) int i32x4;
typedef __attribute__((ext_vector_type(4))) float f32x4;

#define NROWS 8192    // 16*512
#define NCODES 4096
#define DIM 4096
#define BK 128
#define KSTEPS (DIM / BK)   // 32
#define BM 256
#define BN 256

// ---------------- workspace layout (bytes) ----------------
#define OFF_A      0UL
#define OFF_B      33554432UL
#define OFF_NORMS  50331648UL
#define OFF_RN     50348032UL
#define OFF_AMIN   50380800UL
#define OFF_COUNTS 50446336UL

__device__ __forceinline__ void stage16(const void* g, void* l) {
  __builtin_amdgcn_global_load_lds(
      (const __attribute__((address_space(1))) u32*)g,
      (__attribute__((address_space(3))) u32*)l, 16, 0, 0);
}

// float -> OCP e4m3fn, RNE, saturate to 448. Data is finite (no NaN path).
__device__ __forceinline__ u32 f2fp8(float f) {
  u32 u = __float_as_uint(f);
  u32 sign = (u >> 24) & 0x80u;
  u32 mag = u & 0x7FFFFFFFu;
  if (mag > 0x43E00000u) mag = 0x43E00000u;          // sat to 448
  u32 b;
  if (mag < 0x3C800000u) {                            // < 2^-6 : subnormal
    b = (u32)__float2int_rn(__uint_as_float(mag) * 512.0f);
  } else {
    u32 m = mag + 0x7FFFFu + ((mag >> 20) & 1u);      // RNE at 20-bit boundary
    u32 e = (m >> 23) - 127u;
    b = (((e + 7u) << 3) | ((m >> 20) & 7u)) & 0x7Fu;
  }
  return sign | b;
}

__device__ __forceinline__ u32 pack4(float4 v) {
  return f2fp8(v.x) | (f2fp8(v.y) << 8) | (f2fp8(v.z) << 16) | (f2fp8(v.w) << 24);
}

__device__ __forceinline__ float waveRed(float s) {
#pragma unroll
  for (int off = 32; off > 0; off >>= 1) s += __shfl_down(s, off);
  return s;
}

__device__ __forceinline__ i32x8 comb(i32x4 lo, i32x4 hi) {
  i32x8 r;
  r[0] = lo[0]; r[1] = lo[1]; r[2] = lo[2]; r[3] = lo[3];
  r[4] = hi[0]; r[5] = hi[1]; r[6] = hi[2]; r[7] = hi[3];
  return r;
}

// ---------------- inputs: fp32 -> fp8 + ||x||^2 per row (+ amin init) -------
__global__ void k_cvtA(const float4* __restrict__ in, u32* __restrict__ outA,
                       float* __restrict__ rn, u64* __restrict__ amin) {
  int r = blockIdx.x;
  if (threadIdx.x == 64) amin[r] = ~0ULL;   // fold k_init: one launch fewer
  const float4* src = in + (size_t)r * (DIM / 4);
  u32* dst = outA + (size_t)r * (DIM / 4);
  float s = 0.0f;
#pragma unroll
  for (int q = 0; q < 4; ++q) {
    int j = q * 256 + threadIdx.x;
    float4 v = src[j];
    s += v.x * v.x + v.y * v.y + v.z * v.z + v.w * v.w;
    dst[j] = pack4(v);
  }
  s = waveRed(s);
  __shared__ float red[4];
  int wid = threadIdx.x >> 6, lane = threadIdx.x & 63;
  if (lane == 0) red[wid] = s;
  __syncthreads();
  if (threadIdx.x == 0) rn[r] = red[0] + red[1] + red[2] + red[3];
}

// ---------------- codebook: fp32 -> fp8*4096 + ||e||^2 (+ counts init) ------
__global__ void k_cvtB(const float* __restrict__ cb, u32* __restrict__ Bb,
                       float* __restrict__ norms, u32* __restrict__ counts) {
  int row = blockIdx.x;
  if (threadIdx.x == 64) counts[row] = 0u;
  const float4* src = (const float4*)(cb + (size_t)row * DIM);
  u32* dst = Bb + (size_t)row * (DIM / 4);
  float s = 0.0f;
#pragma unroll
  for (int q = 0; q < 4; ++q) {
    int j = q * 256 + threadIdx.x;
    float4 v = src[j];
    s += v.x * v.x + v.y * v.y + v.z * v.z + v.w * v.w;
    float4 sv;
    sv.x = v.x * 4096.0f; sv.y = v.y * 4096.0f;
    sv.z = v.z * 4096.0f; sv.w = v.w * 4096.0f;
    dst[j] = pack4(sv);
  }
  s = waveRed(s);
  __shared__ float red[4];
  int wid = threadIdx.x >> 6, lane = threadIdx.x & 63;
  if (lane == 0) red[wid] = s;
  __syncthreads();
  if (threadIdx.x == 0) norms[row] = red[0] + red[1] + red[2] + red[3];
}

// ---------------- MX-fp8 GEMM (x . e^T) + per-row argmin ----------------
// 256x256 tile, BK=128 fp8, 8 waves (2 M x 4 N), wave tile 128x64,
// 16x16x128 f8f6f4 MFMA, unit scales. Chunk swizzle (pre-swizzled global
// source, linear LDS dest, swizzled reads). 8-phase m201-style schedule.
// ADDRESSING AT MINIMUM REGISTER COST (R11/R12 spilled from fat/generic
// pointers: arch-VGPR side must fit in 128 because acc[8][4]=128 AGPR):
//  - staging: ONE 32-bit per-lane voff (+=128/tile); 64-row chunk
//    offsets are uniform SGPR bases (Ab0 + j*262144)
//  - ds_reads: four 32-bit LDS offsets; every address is
//    shared-base + offset + compile-time literal -> ds_read_b128 offset:N
//  - buffer ids are macro literals (R6-R9 lesson)
__launch_bounds__(512, 1)
__global__ void k_gemm_argmin(const u8* __restrict__ A,
                              const u8* __restrict__ B,
                              const float* __restrict__ norms,
                              u64* __restrict__ amin) {
  __shared__ u8 As[2 * BM * BK];   // 64 KiB (2 buffers x 32 KiB)
  __shared__ u8 Bs[2 * BN * BK];   // 64 KiB

  const int bm = blockIdx.x;
  const int bn = blockIdx.y;

  const int tid = threadIdx.x;
  const int w = tid >> 6;
  const int lane = tid & 63;
  const int wr = w >> 2, wc = w & 3;   // 2 x 4 wave grid
  const int g = lane >> 4, c = lane & 15;

  // stage-side swizzle: thread fills LDS chunk (tid&7) of row j*64+(tid>>3);
  // fetches global chunk (tid&7) ^ (row&7); row&7 == (tid>>3)&7 for all j.
  const int colb = (((tid & 7) ^ ((tid >> 3) & 7)) << 4);
  const int srow = tid >> 3;

  // uniform (SGPR) bases; ONE per-lane 32-bit staging offset
  const u8* Ab0 = A + (size_t)bm * BM * DIM;
  const u8* Bb0 = B + (size_t)bn * BN * DIM;
  u32 voff = (u32)(srow * DIM + colb);
  char* ldsA = (char*)As + tid * 16;
  char* ldsB = (char*)Bs + tid * 16;

  // read-side swizzle: fragment row&7 == c&7; halves at colo and colo^16.
  const u32 colo = (u32)(((2 * g) ^ (c & 7)) << 4);
  const u32 oA = (u32)(wr * 128 + c) * BK + colo;
  const u32 oAx = oA ^ 16u;
  const u32 oB = (u32)(wc * 64 + c) * BK + colo;
  const u32 oBx = oB ^ 16u;

  f32x4 acc[8][4] = {};

  // all literals: buf*32768 + frag*2048 (< 64 KiB ds imm)
#define RD_A(b_, m_) comb(*(const i32x4*)(As + oA + ((b_)*32768 + (m_)*2048)),  \
                          *(const i32x4*)(As + oAx + ((b_)*32768 + (m_)*2048)))
#define RD_B(b_, n_) comb(*(const i32x4*)(Bs + oB + ((b_)*32768 + (n_)*2048)),  \
                          *(const i32x4*)(Bs + oBx + ((b_)*32768 + (n_)*2048)))

#define STAGE(buf)                                                        \
  {                                                                       \
    stage16(Ab0 + voff,          ldsA + (buf)*32768 + 0 * 8192);          \
    stage16(Ab0 + 262144 + voff, ldsA + (buf)*32768 + 1 * 8192);          \
    stage16(Ab0 + 524288 + voff, ldsA + (buf)*32768 + 2 * 8192);          \
    stage16(Ab0 + 786432 + voff, ldsA + (buf)*32768 + 3 * 8192);          \
    stage16(Bb0 + voff,          ldsB + (buf)*32768 + 0 * 8192);          \
    stage16(Bb0 + 262144 + voff, ldsB + (buf)*32768 + 1 * 8192);          \
    stage16(Bb0 + 524288 + voff, ldsB + (buf)*32768 + 2 * 8192);          \
    stage16(Bb0 + 786432 + voff, ldsB + (buf)*32768 + 3 * 8192);          \
    voff += BK;                                                           \
  }

#define MF(a, b_, cc) __builtin_amdgcn_mfma_scale_f32_16x16x128_f8f6f4(   \
    a, b_, cc, 0, 0, 0, 0x7F7F7F7F, 0, 0x7F7F7F7F)

#define PHTAIL(m0, m1)                                                    \
    __builtin_amdgcn_s_barrier();                                         \
    asm volatile("s_waitcnt lgkmcnt(0)" ::: "memory");                    \
    __builtin_amdgcn_sched_barrier(0);                                    \
    __builtin_amdgcn_s_setprio(1);                                        \
    acc[m0][0] = MF(a0, bv0, acc[m0][0]);                                 \
    acc[m0][1] = MF(a0, bv1, acc[m0][1]);                                 \
    acc[m0][2] = MF(a0, bv2, acc[m0][2]);                                 \
    acc[m0][3] = MF(a0, bv3, acc[m0][3]);                                 \
    acc[m1][0] = MF(a1, bv0, acc[m1][0]);                                 \
    acc[m1][1] = MF(a1, bv1, acc[m1][1]);                                 \
    acc[m1][2] = MF(a1, bv2, acc[m1][2]);                                 \
    acc[m1][3] = MF(a1, bv3, acc[m1][3]);                                 \
    __builtin_amdgcn_s_setprio(0);                                        \
    __builtin_amdgcn_s_barrier();

// One K-tile from buffer b (literal 0/1); stg literal 0/1 controls
// whether the next tile is staged into buffer b^1 during phase 0.
#define TILE(b, stg)                                                      \
  {                                                                       \
    i32x8 bv0, bv1, bv2, bv3, a0, a1;                                     \
    bv0 = RD_B(b, 0);                                                     \
    bv1 = RD_B(b, 1);                                                     \
    bv2 = RD_B(b, 2);                                                     \
    bv3 = RD_B(b, 3);                                                     \
    a0 = RD_A(b, 0);                                                      \
    a1 = RD_A(b, 1);                                                      \
    if (stg) STAGE((b) ^ 1);                                              \
    PHTAIL(0, 1)                                                          \
    a0 = RD_A(b, 2);                                                      \
    a1 = RD_A(b, 3);                                                      \
    PHTAIL(2, 3)                                                          \
    a0 = RD_A(b, 4);                                                      \
    a1 = RD_A(b, 5);                                                      \
    PHTAIL(4, 5)                                                          \
    a0 = RD_A(b, 6);                                                      \
    a1 = RD_A(b, 7);                                                      \
    PHTAIL(6, 7)                                                          \
  }

#define VM0BAR()                                                          \
  asm volatile("s_waitcnt vmcnt(0)" ::: "memory");                        \
  __builtin_amdgcn_s_barrier();                                           \
  __builtin_amdgcn_sched_barrier(0);

  // ---- prologue: stage tile 0 into buffer 0 ----
  STAGE(0);
  VM0BAR();

#pragma unroll 1
  for (int kt2 = 0; kt2 < 15; ++kt2) {
    TILE(0, 1);   // compute tile 2k from buf0; stage 2k+1 -> buf1
    VM0BAR();     // buf1 landed (issued 4 phases ago: drain ~free)
    TILE(1, 1);   // compute tile 2k+1 from buf1; stage 2k+2 -> buf0
    VM0BAR();     // buf0 landed
  }
  TILE(0, 1);     // tile 30; stage 31 -> buf1
  VM0BAR();
  TILE(1, 0);     // tile 31, no stage

#undef RD_A
#undef RD_B
#undef STAGE
#undef MF
#undef PHTAIL
#undef TILE
#undef VM0BAR

  // epilogue: d = ||e||^2 - (2/4096)*acc ; argmin over this block's 256 cols
  const int rowBase = bm * BM + wr * 128;
  const int colBase = bn * BN + wc * 64;
  float nr[4];
#pragma unroll
  for (int n = 0; n < 4; ++n) nr[n] = norms[colBase + n * 16 + c];

#pragma unroll
  for (int m = 0; m < 8; ++m) {
#pragma unroll
    for (int j = 0; j < 4; ++j) {
      u64 key = ~0ULL;
#pragma unroll
      for (int n = 0; n < 4; ++n) {
        float d = nr[n] - acc[m][n][j] * 4.8828125e-4f;   // 2/4096
        u32 u = __float_as_uint(d);
        u = (u & 0x80000000u) ? ~u : (u | 0x80000000u);
        u64 k2 = ((u64)u << 32) | (u32)(colBase + n * 16 + c);
        if (k2 < key) key = k2;
      }
#pragma unroll
      for (int off = 1; off < 16; off <<= 1) {
        u64 o = __shfl_xor(key, off);
        if (o < key) key = o;
      }
      if (c == 0) atomicMin(&amin[rowBase + m * 16 + g * 4 + j], key);
    }
  }
}

// ---------------- gather -> output + counts ----------------
__global__ void k_out(const float4* __restrict__ cb, const u64* __restrict__ amin,
                      float4* __restrict__ out, u32* __restrict__ counts) {
  int r = blockIdx.x;
  u32 idx = (u32)(amin[r] & 0xFFFFFFFFu);
  if (threadIdx.x == 0) atomicAdd(&counts[idx], 1u);
  const float4* crow = cb + (size_t)idx * (DIM / 4);
  float4* orow = out + (size_t)r * (DIM / 4);
#pragma unroll
  for (int q = 0; q < 4; ++q) {
    int j = q * 256 + threadIdx.x;
    orow[j] = crow[j];
  }
}

// ---------------- finalize: loss (from distances) + perplexity ----------------
__global__ void k_final(const u32* __restrict__ counts, const u64* __restrict__ amin,
                        const float* __restrict__ rn, float* __restrict__ out) {
  float acc = 0.0f;
  for (int r = threadIdx.x; r < NROWS; r += 256) {
    u32 u = (u32)(amin[r] >> 32);
    u32 b = (u & 0x80000000u) ? (u & 0x7FFFFFFFu) : ~u;  // undo sortable map
    acc += __uint_as_float(b) + rn[r];   // d_min + ||x||^2 = ||x - e||^2
  }
  float ent = 0.0f;
  for (int i = threadIdx.x; i < NCODES; i += 256) {
    float p = (float)counts[i] * (1.0f / (float)NROWS);
    ent -= p * logf(p + 1e-10f);
  }
  acc = waveRed(acc);
  ent = waveRed(ent);
  __shared__ float ra[4], re[4];
  int wid = threadIdx.x >> 6, lane = threadIdx.x & 63;
  if (lane == 0) { ra[wid] = acc; re[wid] = ent; }
  __syncthreads();
  if (threadIdx.x == 0) {
    float sse = ra[0] + ra[1] + ra[2] + ra[3];
    float e = re[0] + re[1] + re[2] + re[3];
    out[(size_t)NROWS * DIM] = 1.25f * sse * (1.0f / (float)((size_t)NROWS * DIM));
    out[(size_t)NROWS * DIM + 1] = expf(e);
  }
}

extern "C" void kernel_launch(void* const* d_in, const int* in_sizes, int n_in,
                              void* d_out, int out_size, void* d_ws, size_t ws_size,
                              hipStream_t stream) {
  const float* d_inputs = (const float*)d_in[0];
  const float* d_cb = (const float*)d_in[1];
  float* out = (float*)d_out;
  char* ws = (char*)d_ws;

  u8* A = (u8*)(ws + OFF_A);
  u8* B = (u8*)(ws + OFF_B);
  float* norms = (float*)(ws + OFF_NORMS);
  float* rn = (float*)(ws + OFF_RN);
  u64* amin = (u64*)(ws + OFF_AMIN);
  u32* counts = (u32*)(ws + OFF_COUNTS);

  k_cvtA<<<NROWS, 256, 0, stream>>>((const float4*)d_inputs, (u32*)A, rn, amin);
  k_cvtB<<<NCODES, 256, 0, stream>>>(d_cb, (u32*)B, norms, counts);
  dim3 grid(NROWS / BM, NCODES / BN);
  k_gemm_argmin<<<grid, 512, 0, stream>>>(A, B, norms, amin);
  k_out<<<NROWS, 256, 0, stream>>>((const float4*)d_cb, amin, (float4*)out, counts);
  k_final<<<1, 256, 0, stream>>>(counts, amin, rn, out);
}